// Round 1
// baseline (116.799 us; speedup 1.0000x reference)
//
#include <hip/hip_runtime.h>
#include <hip/hip_bf16.h>
#include <math.h>

// Problem constants (static config in reference)
#define NT      4096          // B*T
#define DD      1024          // D
#define EE      8             // experts
#define KK      2             // top-k
#define CAP     1280          // EXP_CAP
#define CBN     (NT * EE * CAP)   // 41,943,040 elements per big output

// ---------------------------------------------------------------------------
// Kernel A: router logits + top-2 + softmax(top-2).
// One wave (64 lanes) per token; w_router (8x1024 f32 = 32KB) staged in LDS.
// ---------------------------------------------------------------------------
__global__ __launch_bounds__(256) void logits_topk_kernel(
    const float* __restrict__ x,        // (NT, D)
    const float* __restrict__ w,        // (E, D)
    int* __restrict__ e0, int* __restrict__ e1,
    float* __restrict__ p0, float* __restrict__ p1)
{
    __shared__ float wl[EE * DD];       // 32 KB

    // cooperative load of w_router into LDS (float4)
    for (int i = threadIdx.x; i < EE * DD / 4; i += 256) {
        reinterpret_cast<float4*>(wl)[i] = reinterpret_cast<const float4*>(w)[i];
    }
    __syncthreads();

    const int wave  = threadIdx.x >> 6;
    const int lane  = threadIdx.x & 63;
    const int wgid  = blockIdx.x * 4 + wave;
    const int wtot  = gridDim.x * 4;

    for (int t = wgid; t < NT; t += wtot) {
        const float4* xt = reinterpret_cast<const float4*>(x + (size_t)t * DD);
        float acc[EE];
        #pragma unroll
        for (int e = 0; e < EE; ++e) acc[e] = 0.0f;

        // D/4 = 256 float4 elements, strided by 64 lanes -> 4 iters/lane
        for (int i = lane; i < DD / 4; i += 64) {
            const float4 xv = xt[i];
            #pragma unroll
            for (int e = 0; e < EE; ++e) {
                const float4 wv = reinterpret_cast<const float4*>(wl + e * DD)[i];
                acc[e] += xv.x * wv.x + xv.y * wv.y + xv.z * wv.z + xv.w * wv.w;
            }
        }

        // wave-reduce each expert's partial sum (64 lanes)
        #pragma unroll
        for (int e = 0; e < EE; ++e) {
            float v = acc[e];
            #pragma unroll
            for (int off = 32; off > 0; off >>= 1) v += __shfl_xor(v, off);
            acc[e] = v;
        }

        if (lane == 0) {
            // top-2 (ties -> lower index, matching jax.lax.top_k)
            int b0 = 0; float l0 = acc[0];
            #pragma unroll
            for (int e = 1; e < EE; ++e) { if (acc[e] > l0) { l0 = acc[e]; b0 = e; } }
            int b1 = -1; float l1 = -INFINITY;
            #pragma unroll
            for (int e = 0; e < EE; ++e) { if (e != b0 && acc[e] > l1) { l1 = acc[e]; b1 = e; } }

            const float z  = expf(l1 - l0);      // l1 <= l0, z in (0,1]
            const float pa = 1.0f / (1.0f + z);
            const float pb = z * pa;

            e0[t] = b0; e1[t] = b1;
            p0[t] = pa; p1[t] = pb;
        }
    }
}

// ---------------------------------------------------------------------------
// Kernel B: ordered rank / capacity drop. Single wave.
// Assignment order j = k*NT + t (k-major), matching the reference cumsum.
// Each lane processes 128 consecutive j's. Per-expert counters packed as
// 8 x 16-bit fields across two u64 registers (no runtime-indexed arrays).
// ---------------------------------------------------------------------------
__global__ __launch_bounds__(64) void rank_kernel(
    const int* __restrict__ e0, const int* __restrict__ e1,
    int* __restrict__ slot,              // (K*NT), -1 if dropped
    float* __restrict__ used_cap_out)    // d_out[0..7]
{
    const int lane = threadIdx.x;        // 0..63
    const int base_j = lane * 128;       // 8192 / 64

    unsigned long long ca = 0ull, cb = 0ull;   // experts 0-3 / 4-7, 16b fields
    for (int i = 0; i < 128; ++i) {
        const int j = base_j + i;
        const int e = (j < NT) ? e0[j] : e1[j - NT];
        if (e < 4) ca += 1ull << (16 * e);
        else       cb += 1ull << (16 * (e - 4));
    }

    // inclusive scan across lanes
    unsigned long long sa = ca, sb = cb;
    for (int off = 1; off < 64; off <<= 1) {
        const unsigned long long ta = __shfl_up(sa, off);
        const unsigned long long tb = __shfl_up(sb, off);
        if (lane >= off) { sa += ta; sb += tb; }
    }
    const unsigned long long xa = sa - ca, xb = sb - cb;      // exclusive
    const unsigned long long tota = __shfl(sa, 63);
    const unsigned long long totb = __shfl(sb, 63);

    // replay with running offsets
    unsigned long long ra = xa, rb = xb;
    for (int i = 0; i < 128; ++i) {
        const int j = base_j + i;
        const int e = (j < NT) ? e0[j] : e1[j - NT];
        int rank;
        if (e < 4) { rank = (int)((ra >> (16 * e)) & 0xFFFF);       ra += 1ull << (16 * e); }
        else       { rank = (int)((rb >> (16 * (e - 4))) & 0xFFFF); rb += 1ull << (16 * (e - 4)); }
        slot[j] = (rank < CAP) ? rank : -1;
    }

    if (lane == 0) {
        #pragma unroll
        for (int e = 0; e < EE; ++e) {
            const int tot = (e < 4) ? (int)((tota >> (16 * e)) & 0xFFFF)
                                    : (int)((totb >> (16 * (e - 4))) & 0xFFFF);
            used_cap_out[e] = (float)((tot < CAP) ? tot : CAP);
        }
    }
}

// ---------------------------------------------------------------------------
// Kernel C: scatter the <=8192 nonzero (weight, mask) entries.
// Output layout (all f32): [0..7]=used_cap, [8 .. 8+CBN)=cb_weight,
// [8+CBN .. 8+2*CBN)=sec_mask.
// ---------------------------------------------------------------------------
__global__ __launch_bounds__(256) void scatter_kernel(
    const int* __restrict__ slot,
    const int* __restrict__ e0, const int* __restrict__ e1,
    const float* __restrict__ p0, const float* __restrict__ p1,
    float* __restrict__ out)
{
    const int j = blockIdx.x * 256 + threadIdx.x;
    if (j >= KK * NT) return;
    const int s = slot[j];
    if (s < 0) return;

    const int t = (j < NT) ? j : (j - NT);
    const int e = (j < NT) ? e0[t] : e1[t];
    const float p = (j < NT) ? p0[t] : p1[t];
    if (p == 0.0f) return;  // sec_mask = (cb_weight != 0)

    const size_t idx = (size_t)t * (EE * CAP) + (size_t)e * CAP + (size_t)s;
    out[8 + idx] = p;
    out[8 + (size_t)CBN + idx] = 1.0f;
}

// ---------------------------------------------------------------------------
extern "C" void kernel_launch(void* const* d_in, const int* in_sizes, int n_in,
                              void* d_out, int out_size, void* d_ws, size_t ws_size,
                              hipStream_t stream) {
    const float* x = (const float*)d_in[0];     // (B,T,D) f32
    const float* w = (const float*)d_in[1];     // (E,D)   f32
    float* out = (float*)d_out;

    // workspace layout
    char* ws = (char*)d_ws;
    int*   e0   = (int*)(ws);                    // 16 KB
    int*   e1   = (int*)(ws + 16 * 1024);        // 16 KB
    float* p0   = (float*)(ws + 32 * 1024);      // 16 KB
    float* p1   = (float*)(ws + 48 * 1024);      // 16 KB
    int*   slot = (int*)(ws + 64 * 1024);        // 32 KB

    // 1) zero the entire output (dominant cost: 335.5 MB of writes)
    hipMemsetAsync(d_out, 0, (size_t)out_size * sizeof(float), stream);

    // 2) router logits + top-2 + softmax
    logits_topk_kernel<<<256, 256, 0, stream>>>(x, w, e0, e1, p0, p1);

    // 3) ordered ranking / capacity drop / used_cap
    rank_kernel<<<1, 64, 0, stream>>>(e0, e1, slot, out);

    // 4) scatter nonzeros
    scatter_kernel<<<(KK * NT + 255) / 256, 256, 0, stream>>>(slot, e0, e1, p0, p1, out);
}

// Round 2
// 97.858 us; speedup vs baseline: 1.1936x; 1.1936x over previous
//
#include <hip/hip_runtime.h>
#include <hip/hip_bf16.h>
#include <math.h>

// Problem constants (static config in reference)
#define NT      4096              // B*T
#define DD      1024              // D
#define EE      8                 // experts
#define KK      2                 // top-k
#define CAP     1280              // EXP_CAP
#define CBN     (NT * EE * CAP)   // 41,943,040 elements per big output

#define NBL     64                // logits blocks (first)
#define NBZ     960               // zero-fill blocks
#define ZTOT    20971520ull       // (out_size - 8)/4 float4 elements to zero

// LDS index swizzle (involution): spreads per-thread contiguous-32 walks
// across all banks. bank = (low5 ^ (j>>5))&31 -> conflict-free both ways.
__device__ __forceinline__ int swz(int j) { return j ^ ((j >> 5) & 31); }

// ---------------------------------------------------------------------------
// Kernel 1: fused zero-fill (335.5 MB, the roofline cost) + router logits /
// top-2 / softmax. Blocks [0,NBL) do logits; blocks [NBL,NBL+NBZ) zero-fill.
// The read-bound logits work hides under the chip-wide write-bound fill.
// ---------------------------------------------------------------------------
__global__ __launch_bounds__(256) void zero_logits_kernel(
    const float* __restrict__ x,        // (NT, D)
    const float* __restrict__ w,        // (E, D)
    float* __restrict__ out,
    int* __restrict__ e0, int* __restrict__ e1,
    float* __restrict__ p0, float* __restrict__ p1)
{
    __shared__ float wl[EE * DD];       // 32 KB (allocated for all blocks)

    if (blockIdx.x >= NBL) {
        // ---- zero-fill role: out[8 .. 8+2*CBN) via float4 grid-stride ----
        const float4 zv = make_float4(0.f, 0.f, 0.f, 0.f);
        float4* dst = reinterpret_cast<float4*>(out + 8);
        size_t i = (size_t)(blockIdx.x - NBL) * 256 + threadIdx.x;
        const size_t stride = (size_t)NBZ * 256;
        for (; i < ZTOT; i += stride) dst[i] = zv;
        return;
    }

    // ---- logits role ----
    for (int i = threadIdx.x; i < EE * DD / 4; i += 256)
        reinterpret_cast<float4*>(wl)[i] = reinterpret_cast<const float4*>(w)[i];
    __syncthreads();

    const int wave = threadIdx.x >> 6;
    const int lane = threadIdx.x & 63;
    const int wid  = blockIdx.x * 4 + wave;     // 0 .. NBL*4-1 (256 waves)

    for (int t = wid; t < NT; t += NBL * 4) {
        const float4* xt = reinterpret_cast<const float4*>(x + (size_t)t * DD);
        float acc[EE];
        #pragma unroll
        for (int e = 0; e < EE; ++e) acc[e] = 0.0f;

        #pragma unroll
        for (int ii = 0; ii < DD / 4 / 64; ++ii) {      // 4 iters
            const int i = ii * 64 + lane;
            const float4 xv = xt[i];
            #pragma unroll
            for (int e = 0; e < EE; ++e) {
                const float4 wv = reinterpret_cast<const float4*>(wl + e * DD)[i];
                acc[e] += xv.x * wv.x + xv.y * wv.y + xv.z * wv.z + xv.w * wv.w;
            }
        }

        #pragma unroll
        for (int e = 0; e < EE; ++e) {
            float v = acc[e];
            #pragma unroll
            for (int off = 32; off > 0; off >>= 1) v += __shfl_xor(v, off);
            acc[e] = v;
        }

        if (lane == 0) {
            int b0 = 0; float l0 = acc[0];
            #pragma unroll
            for (int e = 1; e < EE; ++e) { if (acc[e] > l0) { l0 = acc[e]; b0 = e; } }
            int b1 = -1; float l1 = -INFINITY;
            #pragma unroll
            for (int e = 0; e < EE; ++e) { if (e != b0 && acc[e] > l1) { l1 = acc[e]; b1 = e; } }

            const float z  = expf(l1 - l0);     // l1 <= l0
            const float pa = 1.0f / (1.0f + z);
            const float pb = z * pa;

            e0[t] = b0; e1[t] = b1;
            p0[t] = pa; p1[t] = pb;
        }
    }
}

// ---------------------------------------------------------------------------
// Kernel 2: fused ordered rank / capacity drop / used_cap / scatter.
// One block, 256 threads. Assignment order j = k*NT + t. Each thread owns 32
// contiguous j's; per-expert counts packed 8x16-bit in two u64; shfl scan
// intra-wave + LDS scan across waves; replay emits the scattered stores.
// ---------------------------------------------------------------------------
__global__ __launch_bounds__(256) void rank_scatter_kernel(
    const int* __restrict__ e0, const int* __restrict__ e1,
    const float* __restrict__ p0, const float* __restrict__ p1,
    float* __restrict__ out)
{
    __shared__ int   se[KK * NT];       // 32 KB, swizzled
    __shared__ float sp[KK * NT];       // 32 KB, swizzled
    __shared__ unsigned long long wsumA[4], wsumB[4];

    const int tid = threadIdx.x;

    // coalesced stage (writes are bank-conflict-free under swz)
    for (int i = tid; i < NT; i += 256) {
        se[swz(i)]      = e0[i];
        se[swz(NT + i)] = e1[i];
        sp[swz(i)]      = p0[i];
        sp[swz(NT + i)] = p1[i];
    }
    __syncthreads();

    const int base = tid * 32;
    unsigned long long ca = 0ull, cb = 0ull;    // experts 0-3 / 4-7, 16b fields
    #pragma unroll
    for (int i = 0; i < 32; ++i) {
        const int e = se[swz(base + i)];
        if (e < 4) ca += 1ull << (16 * e);
        else       cb += 1ull << (16 * (e - 4));
    }

    // intra-wave inclusive scan
    unsigned long long sa = ca, sb = cb;
    #pragma unroll
    for (int off = 1; off < 64; off <<= 1) {
        const unsigned long long ta = __shfl_up(sa, off);
        const unsigned long long tb = __shfl_up(sb, off);
        if ((tid & 63) >= off) { sa += ta; sb += tb; }
    }
    const int wv = tid >> 6;
    if ((tid & 63) == 63) { wsumA[wv] = sa; wsumB[wv] = sb; }
    __syncthreads();

    unsigned long long preA = 0ull, preB = 0ull;
    #pragma unroll
    for (int k = 0; k < 4; ++k) {
        if (k < wv) { preA += wsumA[k]; preB += wsumB[k]; }
    }
    unsigned long long ra = preA + sa - ca;     // exclusive prefix, this thread
    unsigned long long rb = preB + sb - cb;

    // replay in ascending j order + scatter
    #pragma unroll
    for (int i = 0; i < 32; ++i) {
        const int j = base + i;
        const int e = se[swz(j)];
        int rank;
        if (e < 4) { rank = (int)((ra >> (16 * e)) & 0xFFFF);       ra += 1ull << (16 * e); }
        else       { rank = (int)((rb >> (16 * (e - 4))) & 0xFFFF); rb += 1ull << (16 * (e - 4)); }
        if (rank < CAP) {
            const float p = sp[swz(j)];
            if (p != 0.0f) {                    // sec_mask == (cb_weight != 0)
                const int t = j & (NT - 1);
                const size_t idx = (size_t)t * (EE * CAP) + (size_t)e * CAP + (size_t)rank;
                out[8 + idx] = p;
                out[8 + (size_t)CBN + idx] = 1.0f;
            }
        }
    }

    // used_cap
    if (tid < EE) {
        const unsigned long long totA = wsumA[0] + wsumA[1] + wsumA[2] + wsumA[3];
        const unsigned long long totB = wsumB[0] + wsumB[1] + wsumB[2] + wsumB[3];
        const int e = tid;
        const int tot = (e < 4) ? (int)((totA >> (16 * e)) & 0xFFFF)
                                : (int)((totB >> (16 * (e - 4))) & 0xFFFF);
        out[e] = (float)((tot < CAP) ? tot : CAP);
    }
}

// ---------------------------------------------------------------------------
extern "C" void kernel_launch(void* const* d_in, const int* in_sizes, int n_in,
                              void* d_out, int out_size, void* d_ws, size_t ws_size,
                              hipStream_t stream) {
    const float* x = (const float*)d_in[0];     // (B,T,D) f32
    const float* w = (const float*)d_in[1];     // (E,D)   f32
    float* out = (float*)d_out;

    char* ws = (char*)d_ws;
    int*   e0 = (int*)(ws);
    int*   e1 = (int*)(ws + 16 * 1024);
    float* p0 = (float*)(ws + 32 * 1024);
    float* p1 = (float*)(ws + 48 * 1024);

    // 1) fused zero-fill (dominant, write-bound) + logits/top2/softmax
    zero_logits_kernel<<<NBL + NBZ, 256, 0, stream>>>(x, w, out, e0, e1, p0, p1);

    // 2) fused ordered rank + capacity + used_cap + scatter (single block)
    rank_scatter_kernel<<<1, 256, 0, stream>>>(e0, e1, p0, p1, out);
}